// Round 8
// baseline (177.573 us; speedup 1.0000x reference)
//
#include <hip/hip_runtime.h>
#include <hip/hip_bf16.h>

#define B_  2
#define S_  512
#define H_  8
#define D_  32
#define DM_ 256
#define HD_ 256
#define NROW 16        // rows per qkv block
#define TI  2          // i-rows per attention block
#define CH  32         // rpe chunk rows staged per buffer

// ---------------------------------------------------------------------------
// Kernel A: QKV projection.  grid = (B*S/NROW, 3), block = 256.
// out layout: (b, h, s, d).  q is pre-scaled by 1/sqrt(D).
// NROW=16 halves weight L2 traffic vs NROW=8 (96 -> 48 MB aggregate).
// ---------------------------------------------------------------------------
__global__ __launch_bounds__(256) void qkv_kernel(
    const float* __restrict__ hid, const float* __restrict__ wq,
    const float* __restrict__ wk, const float* __restrict__ wv,
    float* __restrict__ qo, float* __restrict__ ko, float* __restrict__ vo)
{
  __shared__ __align__(16) float hs[NROW][DM_];
  const int r0 = blockIdx.x * NROW;                 // global row in [0, B*S)
  const float* w   = (blockIdx.y == 0) ? wq : (blockIdx.y == 1) ? wk : wv;
  float*       out = (blockIdx.y == 0) ? qo : (blockIdx.y == 1) ? ko : vo;
  const float mulf = (blockIdx.y == 0) ? 0.17677669529663687f : 1.0f;
  const int tid = threadIdx.x;

  for (int idx = tid; idx < NROW * DM_; idx += 256)
    hs[idx >> 8][idx & 255] = hid[r0 * DM_ + idx];
  __syncthreads();

  float acc[NROW];
  #pragma unroll
  for (int r = 0; r < NROW; ++r) acc[r] = 0.f;
  const float* wp = w + tid;                        // column m = tid
  #pragma unroll 2
  for (int c4 = 0; c4 < DM_ / 4; ++c4) {
    const float w0 = wp[(4 * c4 + 0) * HD_];
    const float w1 = wp[(4 * c4 + 1) * HD_];
    const float w2 = wp[(4 * c4 + 2) * HD_];
    const float w3 = wp[(4 * c4 + 3) * HD_];
    #pragma unroll
    for (int r = 0; r < NROW; ++r) {
      const float4 hv = reinterpret_cast<const float4*>(&hs[r][0])[c4];
      acc[r] = fmaf(hv.x, w0, acc[r]);
      acc[r] = fmaf(hv.y, w1, acc[r]);
      acc[r] = fmaf(hv.z, w2, acc[r]);
      acc[r] = fmaf(hv.w, w3, acc[r]);
    }
  }
  const int h = tid >> 5, d = tid & 31;
  #pragma unroll
  for (int r = 0; r < NROW; ++r) {
    const int g = r0 + r;
    const int b = g >> 9, s = g & (S_ - 1);
    out[((b * H_ + h) * S_ + s) * D_ + d] = acc[r] * mulf;
  }
}

// 4-lane (quad) butterfly sum via DPP: all 4 lanes of the quad get the sum.
__device__ __forceinline__ float red4(float x) {
  int i;
  i = __builtin_amdgcn_mov_dpp(__float_as_int(x), 0xB1, 0xf, 0xf, true); // quad_perm xor1
  x += __int_as_float(i);
  i = __builtin_amdgcn_mov_dpp(__float_as_int(x), 0x4E, 0xf, 0xf, true); // quad_perm xor2
  x += __int_as_float(i);
  return x;
}

// swizzled float4 slot within a CH*D_ rpe chunk (jj = local row, c = 16B col)
#define RSL(jj, c) (((jj) << 3) | ((c) ^ ((jj) & 7)))

// ---------------------------------------------------------------------------
// Kernel B (fused): scores + mask + softmax + attn@V + fc + residual + LN.
// R7 post-mortem: TI=4 cut bytes 550->355 MB but 1 block/CU (8 waves/CU,
// 19.6% occ) cut sustained BW ~2x -> net loss.  Model: t ~ bytes/BW(waves).
// R8 = R6's byte count (TI=2, 550 MB) + 24 waves/CU:
//   CH 64->32 shrinks rpe dbuf 32->16 KB -> LDS ~53 KB -> 3 blocks/CU;
//   launch_bounds(512,6) (85-reg cap, demand ~70) unblocks the 3rd block;
//   bijective XCD-chunk swizzle (512 = 8*64): each XCD owns 64 contiguous
//   i-tiles of ONE batch -> its hot shared set (q 256K + V 256K + fcw 256K)
//   L2-resident under the rpe stream (q/V/fcw reads move L3 -> L2).
// Wave w owns head w; q/V loads amortized over TI=2 i-rows.
// Score mapping: lane=(j4,dq).  attn@V mapping: lane=(j8,dc).
// scores[ii,h,j] = sum_d q'[h,j,d] k[h,i0+ii,d] rpe[i0+ii,j,d];
// mask: j < station OR j == i.
// ---------------------------------------------------------------------------
__global__ __launch_bounds__(512, 6) void attn_fused_kernel(
    const float* __restrict__ rpe, const float* __restrict__ q_ws,
    const float* __restrict__ k_ws, const float* __restrict__ v_ws,
    const int* __restrict__ station_p, const float* __restrict__ fc_w,
    const float* __restrict__ fc_b, const float* __restrict__ hid,
    const float* __restrict__ ln_w, const float* __restrict__ ln_b,
    float* __restrict__ out)
{
  __shared__ __align__(16) float p_smem[TI][H_][S_];      // 32 KB
  __shared__ __align__(16) float rpe_s[2][TI][CH * D_];   // 16 KB, swizzled
  __shared__ __align__(16) float ks[TI][H_ * D_];         // 2 KB
  __shared__ __align__(16) float orow[TI][HD_];           // 2 KB
  __shared__ float sums[TI][H_];
  __shared__ float redm[TI][4];
  __shared__ float redvr[TI][4];

  const int tid  = threadIdx.x;
  const int w    = tid >> 6, lane = tid & 63;
  const int j4   = lane >> 2, dq = lane & 3;        // score mapping
  const int j8   = lane >> 3, dc = lane & 7;        // attn@V mapping
  // XCD-chunk swizzle: grid 512 = 8 XCDs x 64 contiguous tiles (bijective)
  const int n    = ((blockIdx.x & 7) << 6) | (blockIdx.x >> 3);
  const int b    = n >> 8;
  const int i0   = (n & 255) * TI;
  const int HS   = S_ * D_;                         // head stride

  int station = station_p[0];
  station = station > S_ ? S_ : (station < 0 ? 0 : station);
  const bool dx0 = (i0 >= station);
  const bool dx1 = (i0 + 1 >= station);

  const float* qb = q_ws + (size_t)(b * H_) * S_ * D_;
  const float* kb = k_ws + (size_t)(b * H_) * S_ * D_;
  const float* vb = v_ws + (size_t)(b * H_) * S_ * D_;
  const float* rb0 = rpe + ((size_t)(b * S_ + i0) * S_) * D_;
  const float* rb1 = rpe + ((size_t)(b * S_ + i0 + 1) * S_) * D_;

  // stage K rows i0,i0+1 (all 8 heads): exactly 512 elements = 1/thread
  {
    const int ii = tid >> 8, rest = tid & 255;
    const int h = rest >> 5, d = rest & 31;
    ks[ii][rest] = kb[h * HS + (i0 + ii) * D_ + d];
  }
  // stage rpe chunk 0 (swizzled); CH*8=256 float4 per i-row, 2 ii = 1/thread
  const int nc = (station + CH - 1) / CH;           // chunks of CH j
  const int sii = tid >> 8, sidx = tid & 255;       // staging: ii, slot index
  const int sjj = sidx >> 3, scs = sidx & 7;
  const int ssl = RSL(sjj, scs);
  const float* srb = sii ? rb1 : rb0;
  if (nc > 0) {
    reinterpret_cast<float4*>(&rpe_s[0][sii][0])[ssl] =
        reinterpret_cast<const float4*>(srb)[sidx];
  }
  __syncthreads();

  // hoisted K fragments for this wave's head (16 VGPRs)
  const float4 k0a = *reinterpret_cast<const float4*>(&ks[0][w * D_ + dq * 8]);
  const float4 k0b = *reinterpret_cast<const float4*>(&ks[0][w * D_ + dq * 8 + 4]);
  const float4 k1a = *reinterpret_cast<const float4*>(&ks[1][w * D_ + dq * 8]);
  const float4 k1b = *reinterpret_cast<const float4*>(&ks[1][w * D_ + dq * 8 + 4]);
  const float* qh = qb + w * HS;
  float* ph0 = &p_smem[0][w][0];
  float* ph1 = &p_smem[1][w][0];

  // ---- scores: chunked over j; prefetch next chunk before compute ----
  for (int c = 0; c < nc; ++c) {
    if (c) __syncthreads();                         // chunk c staged; c-1 reads done
    if (c + 1 < nc) {                               // stage next chunk (issue early)
      const int buf = (c + 1) & 1;
      reinterpret_cast<float4*>(&rpe_s[buf][sii][0])[ssl] =
          reinterpret_cast<const float4*>(srb + (c + 1) * CH * D_)[sidx];
    }
    const float4* rs0 = reinterpret_cast<const float4*>(&rpe_s[c & 1][0][0]);
    const float4* rs1 = reinterpret_cast<const float4*>(&rpe_s[c & 1][1][0]);
    #pragma unroll
    for (int p = 0; p < CH / 16; ++p) {
      const int jl = p * 16 + j4;                   // local j in chunk
      const int j  = c * CH + jl;                   // j <= 511 always
      const float4 q0 = *reinterpret_cast<const float4*>(qh + j * D_ + dq * 8);
      const float4 q1 = *reinterpret_cast<const float4*>(qh + j * D_ + dq * 8 + 4);
      const float4 ra0 = rs0[RSL(jl, 2 * dq)];
      const float4 ra1 = rs0[RSL(jl, 2 * dq + 1)];
      const float4 rc0 = rs1[RSL(jl, 2 * dq)];
      const float4 rc1 = rs1[RSL(jl, 2 * dq + 1)];
      float s0 = q0.x * k0a.x * ra0.x;
      s0 = fmaf(q0.y * k0a.y, ra0.y, s0);
      s0 = fmaf(q0.z * k0a.z, ra0.z, s0);
      s0 = fmaf(q0.w * k0a.w, ra0.w, s0);
      s0 = fmaf(q1.x * k0b.x, ra1.x, s0);
      s0 = fmaf(q1.y * k0b.y, ra1.y, s0);
      s0 = fmaf(q1.z * k0b.z, ra1.z, s0);
      s0 = fmaf(q1.w * k0b.w, ra1.w, s0);
      float s1 = q0.x * k1a.x * rc0.x;
      s1 = fmaf(q0.y * k1a.y, rc0.y, s1);
      s1 = fmaf(q0.z * k1a.z, rc0.z, s1);
      s1 = fmaf(q0.w * k1a.w, rc0.w, s1);
      s1 = fmaf(q1.x * k1b.x, rc1.x, s1);
      s1 = fmaf(q1.y * k1b.y, rc1.y, s1);
      s1 = fmaf(q1.z * k1b.z, rc1.z, s1);
      s1 = fmaf(q1.w * k1b.w, rc1.w, s1);
      s0 = red4(s0);
      s1 = red4(s1);
      if (dq == 0 && j < station) { ph0[j] = s0; ph1[j] = s1; }
    }
  }
  // diagonal cells j == i0+ii when beyond station (lanes 0..3; rpe/q global)
  if (j4 == 0) {
    if (dx0) {
      const int i = i0;
      const float4 r0 = *reinterpret_cast<const float4*>(rb0 + i * D_ + dq * 8);
      const float4 r1 = *reinterpret_cast<const float4*>(rb0 + i * D_ + dq * 8 + 4);
      const float4 q0 = *reinterpret_cast<const float4*>(qh + i * D_ + dq * 8);
      const float4 q1 = *reinterpret_cast<const float4*>(qh + i * D_ + dq * 8 + 4);
      float s = q0.x * k0a.x * r0.x;
      s = fmaf(q0.y * k0a.y, r0.y, s);
      s = fmaf(q0.z * k0a.z, r0.z, s);
      s = fmaf(q0.w * k0a.w, r0.w, s);
      s = fmaf(q1.x * k0b.x, r1.x, s);
      s = fmaf(q1.y * k0b.y, r1.y, s);
      s = fmaf(q1.z * k0b.z, r1.z, s);
      s = fmaf(q1.w * k0b.w, r1.w, s);
      s = red4(s);
      if (dq == 0) ph0[i] = s;
    }
    if (dx1) {
      const int i = i0 + 1;
      const float4 r0 = *reinterpret_cast<const float4*>(rb1 + i * D_ + dq * 8);
      const float4 r1 = *reinterpret_cast<const float4*>(rb1 + i * D_ + dq * 8 + 4);
      const float4 q0 = *reinterpret_cast<const float4*>(qh + i * D_ + dq * 8);
      const float4 q1 = *reinterpret_cast<const float4*>(qh + i * D_ + dq * 8 + 4);
      float s = q0.x * k1a.x * r0.x;
      s = fmaf(q0.y * k1a.y, r0.y, s);
      s = fmaf(q0.z * k1a.z, r0.z, s);
      s = fmaf(q0.w * k1a.w, r0.w, s);
      s = fmaf(q1.x * k1b.x, r1.x, s);
      s = fmaf(q1.y * k1b.y, r1.y, s);
      s = fmaf(q1.z * k1b.z, r1.z, s);
      s = fmaf(q1.w * k1b.w, r1.w, s);
      s = red4(s);
      if (dq == 0) ph1[i] = s;
    }
  }
  __syncthreads();

  // ---- softmax: wave w handles rows (ii=0,h=w) and (ii=1,h=w) ----
  #pragma unroll
  for (int ii = 0; ii < TI; ++ii) {
    float* pr = &p_smem[ii][w][0];
    const int ig = i0 + ii;
    const bool dxi = (ig >= station);
    float m = -1e30f;
    for (int jj = lane; jj < station; jj += 64) m = fmaxf(m, pr[jj]);
    const float dv = dxi ? pr[ig] : -1e30f;
    m = fmaxf(m, dv);
    #pragma unroll
    for (int o = 32; o; o >>= 1) m = fmaxf(m, __shfl_xor(m, o, 64));
    float sum = 0.f;
    for (int jj = lane; jj < station; jj += 64) {
      const float e = __expf(pr[jj] - m);
      pr[jj] = e;
      sum += e;
    }
    #pragma unroll
    for (int o = 32; o; o >>= 1) sum += __shfl_xor(sum, o, 64);
    if (dxi) {
      const float e = __expf(dv - m);
      sum += e;
      if (lane == 0) pr[ig] = e;
    }
    if (lane == 0) sums[ii][w] = sum;
  }
  __syncthreads();

  // ---- attn @ V: wave w owns head w; each V load feeds both i-rows ----
  float4 a0 = make_float4(0.f, 0.f, 0.f, 0.f);
  float4 a1 = make_float4(0.f, 0.f, 0.f, 0.f);
  {
    const float* vh = vb + w * HS;
    #pragma unroll 4
    for (int jb = 0; jb < station; jb += 8) {
      const int j  = jb + j8;
      const int jc = j < S_ ? j : S_ - 1;
      const float4 v4 = *reinterpret_cast<const float4*>(vh + jc * D_ + dc * 4);
      float pv0 = 0.f, pv1 = 0.f;
      if (j < station) { pv0 = ph0[j]; pv1 = ph1[j]; }
      a0.x = fmaf(pv0, v4.x, a0.x);
      a0.y = fmaf(pv0, v4.y, a0.y);
      a0.z = fmaf(pv0, v4.z, a0.z);
      a0.w = fmaf(pv0, v4.w, a0.w);
      a1.x = fmaf(pv1, v4.x, a1.x);
      a1.y = fmaf(pv1, v4.y, a1.y);
      a1.z = fmaf(pv1, v4.z, a1.z);
      a1.w = fmaf(pv1, v4.w, a1.w);
    }
  }
  // reduce over j8 groups (lane bits 3..5)
  #pragma unroll
  for (int o = 8; o <= 32; o <<= 1) {
    a0.x += __shfl_xor(a0.x, o, 64);
    a0.y += __shfl_xor(a0.y, o, 64);
    a0.z += __shfl_xor(a0.z, o, 64);
    a0.w += __shfl_xor(a0.w, o, 64);
    a1.x += __shfl_xor(a1.x, o, 64);
    a1.y += __shfl_xor(a1.y, o, 64);
    a1.z += __shfl_xor(a1.z, o, 64);
    a1.w += __shfl_xor(a1.w, o, 64);
  }
  if (j8 == 0) {
    // diagonal contributions (exactly once, post-reduction)
    if (dx0) {
      const float pv = ph0[i0];
      const float4 v4 = *reinterpret_cast<const float4*>(vb + w * HS + i0 * D_ + dc * 4);
      a0.x = fmaf(pv, v4.x, a0.x);
      a0.y = fmaf(pv, v4.y, a0.y);
      a0.z = fmaf(pv, v4.z, a0.z);
      a0.w = fmaf(pv, v4.w, a0.w);
    }
    if (dx1) {
      const float pv = ph1[i0 + 1];
      const float4 v4 = *reinterpret_cast<const float4*>(vb + w * HS + (i0 + 1) * D_ + dc * 4);
      a1.x = fmaf(pv, v4.x, a1.x);
      a1.y = fmaf(pv, v4.y, a1.y);
      a1.z = fmaf(pv, v4.z, a1.z);
      a1.w = fmaf(pv, v4.w, a1.w);
    }
    const float inv0 = 1.f / sums[0][w];
    const float inv1 = 1.f / sums[1][w];
    a0.x *= inv0; a0.y *= inv0; a0.z *= inv0; a0.w *= inv0;
    a1.x *= inv1; a1.y *= inv1; a1.z *= inv1; a1.w *= inv1;
    reinterpret_cast<float4*>(&orow[0][w * D_])[dc] = a0;
    reinterpret_cast<float4*>(&orow[1][w * D_])[dc] = a1;
  }
  __syncthreads();

  // ---- fc (thread per output column m=tid, first 4 waves) + residual + LN --
  float f0 = 0.f, f1 = 0.f;
  if (tid < DM_) {
    const float* wp = fc_w + tid;
    #pragma unroll 8
    for (int n4 = 0; n4 < HD_ / 4; ++n4) {
      const float4 o0 = reinterpret_cast<const float4*>(&orow[0][0])[n4];
      const float4 o1 = reinterpret_cast<const float4*>(&orow[1][0])[n4];
      const float w0 = wp[(4 * n4 + 0) * DM_];
      const float w1 = wp[(4 * n4 + 1) * DM_];
      const float w2 = wp[(4 * n4 + 2) * DM_];
      const float w3 = wp[(4 * n4 + 3) * DM_];
      f0 = fmaf(o0.x, w0, f0); f1 = fmaf(o1.x, w0, f1);
      f0 = fmaf(o0.y, w1, f0); f1 = fmaf(o1.y, w1, f1);
      f0 = fmaf(o0.z, w2, f0); f1 = fmaf(o1.z, w2, f1);
      f0 = fmaf(o0.w, w3, f0); f1 = fmaf(o1.w, w3, f1);
    }
    const float bias = fc_b[tid];
    f0 += bias + hid[(size_t)(b * S_ + i0) * DM_ + tid];
    f1 += bias + hid[(size_t)(b * S_ + i0 + 1) * DM_ + tid];
    float s0 = f0, s1 = f1;
    #pragma unroll
    for (int o = 32; o; o >>= 1) {
      s0 += __shfl_xor(s0, o, 64);
      s1 += __shfl_xor(s1, o, 64);
    }
    if (lane == 0) { redm[0][w] = s0; redm[1][w] = s1; }
  }
  __syncthreads();
  const float mu0 = (redm[0][0] + redm[0][1] + redm[0][2] + redm[0][3]) * (1.f / DM_);
  const float mu1 = (redm[1][0] + redm[1][1] + redm[1][2] + redm[1][3]) * (1.f / DM_);
  const float d0 = f0 - mu0, d1 = f1 - mu1;
  if (tid < DM_) {
    float s0 = d0 * d0, s1 = d1 * d1;
    #pragma unroll
    for (int o = 32; o; o >>= 1) {
      s0 += __shfl_xor(s0, o, 64);
      s1 += __shfl_xor(s1, o, 64);
    }
    if (lane == 0) { redvr[0][w] = s0; redvr[1][w] = s1; }
  }
  __syncthreads();
  if (tid < DM_) {
    const float v0 = (redvr[0][0] + redvr[0][1] + redvr[0][2] + redvr[0][3]) * (1.f / DM_);
    const float v1 = (redvr[1][0] + redvr[1][1] + redvr[1][2] + redvr[1][3]) * (1.f / DM_);
    const float lw = ln_w[tid], lb = ln_b[tid];
    out[(size_t)(b * S_ + i0) * DM_ + tid]     = d0 * rsqrtf(v0 + 1e-6f) * lw + lb;
    out[(size_t)(b * S_ + i0 + 1) * DM_ + tid] = d1 * rsqrtf(v1 + 1e-6f) * lw + lb;
  }
}

// ---------------------------------------------------------------------------
extern "C" void kernel_launch(void* const* d_in, const int* in_sizes, int n_in,
                              void* d_out, int out_size, void* d_ws, size_t ws_size,
                              hipStream_t stream) {
  const float* hid = (const float*)d_in[0];
  const float* rpe = (const float*)d_in[1];
  const float* wq  = (const float*)d_in[2];
  const float* wk  = (const float*)d_in[3];
  const float* wv  = (const float*)d_in[4];
  const float* fcw = (const float*)d_in[5];
  const float* fcb = (const float*)d_in[6];
  const float* lnw = (const float*)d_in[7];
  const float* lnb = (const float*)d_in[8];
  const int* station = (const int*)d_in[9];
  float* out = (float*)d_out;

  const size_t per = (size_t)B_ * H_ * S_ * D_;   // 262144 floats
  float* q_ws = (float*)d_ws;
  float* k_ws = q_ws + per;
  float* v_ws = k_ws + per;

  dim3 gA(B_ * S_ / NROW, 3);
  qkv_kernel<<<gA, 256, 0, stream>>>(hid, wq, wk, wv, q_ws, k_ws, v_ws);
  attn_fused_kernel<<<B_ * S_ / TI, 512, 0, stream>>>(
      rpe, q_ws, k_ws, v_ws, station, fcw, fcb, hid, lnw, lnb, out);
}

// Round 9
// 149.251 us; speedup vs baseline: 1.1898x; 1.1898x over previous
//
#include <hip/hip_runtime.h>
#include <hip/hip_bf16.h>

#define B_  2
#define S_  512
#define H_  8
#define D_  32
#define DM_ 256
#define HD_ 256
#define NROW 8         // rows per qkv block
#define TI  2          // i-rows per attention block
#define CH  64         // rpe chunk rows staged per buffer

// ---------------------------------------------------------------------------
// Kernel A: QKV projection.  grid = (B*S/NROW, 3) = 384 blocks >= 256 CUs.
// out layout: (b, h, s, d).  q is pre-scaled by 1/sqrt(D).
// R8 lesson: NROW=16 shrank grid to 192 < 256 CUs -> 7.9% occ, 53.8 us.
// NROW=8 is the measured optimum (weight traffic 96 MB, grid covers chip).
// ---------------------------------------------------------------------------
__global__ __launch_bounds__(256) void qkv_kernel(
    const float* __restrict__ hid, const float* __restrict__ wq,
    const float* __restrict__ wk, const float* __restrict__ wv,
    float* __restrict__ qo, float* __restrict__ ko, float* __restrict__ vo)
{
  __shared__ __align__(16) float hs[NROW][DM_];
  const int r0 = blockIdx.x * NROW;                 // global row in [0, B*S)
  const float* w   = (blockIdx.y == 0) ? wq : (blockIdx.y == 1) ? wk : wv;
  float*       out = (blockIdx.y == 0) ? qo : (blockIdx.y == 1) ? ko : vo;
  const float mulf = (blockIdx.y == 0) ? 0.17677669529663687f : 1.0f;
  const int tid = threadIdx.x;

  for (int idx = tid; idx < NROW * DM_; idx += 256)
    hs[idx >> 8][idx & 255] = hid[r0 * DM_ + idx];
  __syncthreads();

  float acc[NROW] = {0.f, 0.f, 0.f, 0.f, 0.f, 0.f, 0.f, 0.f};
  const float* wp = w + tid;                        // column m = tid
  #pragma unroll 4
  for (int c4 = 0; c4 < DM_ / 4; ++c4) {
    const float w0 = wp[(4 * c4 + 0) * HD_];
    const float w1 = wp[(4 * c4 + 1) * HD_];
    const float w2 = wp[(4 * c4 + 2) * HD_];
    const float w3 = wp[(4 * c4 + 3) * HD_];
    #pragma unroll
    for (int r = 0; r < NROW; ++r) {
      const float4 hv = reinterpret_cast<const float4*>(&hs[r][0])[c4];
      acc[r] = fmaf(hv.x, w0, acc[r]);
      acc[r] = fmaf(hv.y, w1, acc[r]);
      acc[r] = fmaf(hv.z, w2, acc[r]);
      acc[r] = fmaf(hv.w, w3, acc[r]);
    }
  }
  const int h = tid >> 5, d = tid & 31;
  #pragma unroll
  for (int r = 0; r < NROW; ++r) {
    const int g = r0 + r;
    const int b = g >> 9, s = g & (S_ - 1);
    out[((b * H_ + h) * S_ + s) * D_ + d] = acc[r] * mulf;
  }
}

// 4-lane (quad) butterfly sum via DPP: all 4 lanes of the quad get the sum.
__device__ __forceinline__ float red4(float x) {
  int i;
  i = __builtin_amdgcn_mov_dpp(__float_as_int(x), 0xB1, 0xf, 0xf, true); // quad_perm xor1
  x += __int_as_float(i);
  i = __builtin_amdgcn_mov_dpp(__float_as_int(x), 0x4E, 0xf, 0xf, true); // quad_perm xor2
  x += __int_as_float(i);
  return x;
}

// swizzled float4 slot within a CH*D_ rpe chunk (jj = local row, c = 16B col)
#define RSL(jj, c) (((jj) << 3) | ((c) ^ ((jj) & 7)))

// ---------------------------------------------------------------------------
// Kernel B (fused): scores + mask + softmax + attn@V + fc + residual + LN.
// MEASURED OPTIMUM (R6 = session best 148.9 us; R7 TI=4 lost to occupancy
// collapse, R8 CH=32/3-block lost to barrier overhead + squeezed ILP):
//   TI=2 i-rows/block, grid 512, 8 waves, LDS 69 KB -> 2 blocks/CU =
//   16 waves/CU; launch_bounds(512,4) = 128-reg budget (demand ~70, VGPR
//   measured 64-88, NO spill); CH=64 rpe chunks (4 barriers total).
// Byte budget ~550 MB L2 @ ~16-18 TB/s: q 128 + V 128 + fcw 128 + rpe 32
// (floor) + K/hid/out misc.  Wave w owns head w in every phase; q/V/fcw
// loads amortized over both i-rows; rpe staged ONCE per block (no 8x wave
// duplication), double-buffered, XOR-swizzled (row = 128 B = 32 banks ->
// unswizzled column reads would 16-way conflict).
// Score mapping: lane=(j4,dq), 4 dq-lanes cover one j's 128B d-row.
// attn@V mapping: lane=(j8,dc); each V load feeds both i-accumulators.
// scores[ii,h,j] = sum_d q'[h,j,d] k[h,i0+ii,d] rpe[i0+ii,j,d];
// mask: j < station OR j == i.
// Register arrays: compile-time indices ONLY (R2/R3: dynamic -> scratch).
// ---------------------------------------------------------------------------
__global__ __launch_bounds__(512, 4) void attn_fused_kernel(
    const float* __restrict__ rpe, const float* __restrict__ q_ws,
    const float* __restrict__ k_ws, const float* __restrict__ v_ws,
    const int* __restrict__ station_p, const float* __restrict__ fc_w,
    const float* __restrict__ fc_b, const float* __restrict__ hid,
    const float* __restrict__ ln_w, const float* __restrict__ ln_b,
    float* __restrict__ out)
{
  __shared__ __align__(16) float p_smem[TI][H_][S_];      // 32 KB
  __shared__ __align__(16) float rpe_s[2][TI][CH * D_];   // 32 KB, swizzled
  __shared__ __align__(16) float ks[TI][H_ * D_];         // 2 KB
  __shared__ __align__(16) float orow[TI][HD_];           // 2 KB
  __shared__ float sums[TI][H_];
  __shared__ float redm[TI][4];
  __shared__ float redvr[TI][4];

  const int tid  = threadIdx.x;
  const int w    = tid >> 6, lane = tid & 63;
  const int j4   = lane >> 2, dq = lane & 3;        // score mapping
  const int j8   = lane >> 3, dc = lane & 7;        // attn@V mapping
  const int n    = blockIdx.x;                      // 0..511
  const int b    = n >> 8;
  const int i0   = (n & 255) * TI;
  const int HS   = S_ * D_;                         // head stride

  int station = station_p[0];
  station = station > S_ ? S_ : (station < 0 ? 0 : station);
  const bool dx0 = (i0 >= station);
  const bool dx1 = (i0 + 1 >= station);

  const float* qb = q_ws + (size_t)(b * H_) * S_ * D_;
  const float* kb = k_ws + (size_t)(b * H_) * S_ * D_;
  const float* vb = v_ws + (size_t)(b * H_) * S_ * D_;
  const float* rb0 = rpe + ((size_t)(b * S_ + i0) * S_) * D_;
  const float* rb1 = rpe + ((size_t)(b * S_ + i0 + 1) * S_) * D_;

  // stage K rows i0,i0+1 (all 8 heads): exactly 512 elements = 1/thread
  {
    const int ii = tid >> 8, rest = tid & 255;
    const int h = rest >> 5, d = rest & 31;
    ks[ii][rest] = kb[h * HS + (i0 + ii) * D_ + d];
  }
  // stage rpe chunk 0 (swizzled); 512 float4 per i-row = 1/thread each
  const int nc = (station + CH - 1) >> 6;           // chunks of 64 j
  {
    const int jj = tid >> 3, cs = tid & 7;
    const int sl = RSL(jj, cs);
    if (nc > 0) {
      reinterpret_cast<float4*>(&rpe_s[0][0][0])[sl] =
          reinterpret_cast<const float4*>(rb0)[tid];
      reinterpret_cast<float4*>(&rpe_s[0][1][0])[sl] =
          reinterpret_cast<const float4*>(rb1)[tid];
    }
  }
  __syncthreads();

  // hoisted K fragments for this wave's head (16 VGPRs)
  const float4 k0a = *reinterpret_cast<const float4*>(&ks[0][w * D_ + dq * 8]);
  const float4 k0b = *reinterpret_cast<const float4*>(&ks[0][w * D_ + dq * 8 + 4]);
  const float4 k1a = *reinterpret_cast<const float4*>(&ks[1][w * D_ + dq * 8]);
  const float4 k1b = *reinterpret_cast<const float4*>(&ks[1][w * D_ + dq * 8 + 4]);
  const float* qh = qb + w * HS;
  float* ph0 = &p_smem[0][w][0];
  float* ph1 = &p_smem[1][w][0];

  // ---- scores: chunked over j; all waves consume the staged chunk ----
  for (int c = 0; c < nc; ++c) {
    if (c) __syncthreads();                         // chunk c staged; c-1 reads done
    if (c + 1 < nc) {                               // stage next chunk (issue early)
      const int jj = tid >> 3, cs = tid & 7;
      const int sl = RSL(jj, cs);
      const int buf = (c + 1) & 1;
      reinterpret_cast<float4*>(&rpe_s[buf][0][0])[sl] =
          reinterpret_cast<const float4*>(rb0 + (c + 1) * CH * D_)[tid];
      reinterpret_cast<float4*>(&rpe_s[buf][1][0])[sl] =
          reinterpret_cast<const float4*>(rb1 + (c + 1) * CH * D_)[tid];
    }
    const float4* rs0 = reinterpret_cast<const float4*>(&rpe_s[c & 1][0][0]);
    const float4* rs1 = reinterpret_cast<const float4*>(&rpe_s[c & 1][1][0]);
    #pragma unroll
    for (int p = 0; p < CH / 16; ++p) {
      const int jl = p * 16 + j4;                   // local j in chunk
      const int j  = c * CH + jl;                   // j <= 511 always
      const float4 q0 = *reinterpret_cast<const float4*>(qh + j * D_ + dq * 8);
      const float4 q1 = *reinterpret_cast<const float4*>(qh + j * D_ + dq * 8 + 4);
      const float4 ra0 = rs0[RSL(jl, 2 * dq)];
      const float4 ra1 = rs0[RSL(jl, 2 * dq + 1)];
      const float4 rb0v = rs1[RSL(jl, 2 * dq)];
      const float4 rb1v = rs1[RSL(jl, 2 * dq + 1)];
      float s0 = q0.x * k0a.x * ra0.x;
      s0 = fmaf(q0.y * k0a.y, ra0.y, s0);
      s0 = fmaf(q0.z * k0a.z, ra0.z, s0);
      s0 = fmaf(q0.w * k0a.w, ra0.w, s0);
      s0 = fmaf(q1.x * k0b.x, ra1.x, s0);
      s0 = fmaf(q1.y * k0b.y, ra1.y, s0);
      s0 = fmaf(q1.z * k0b.z, ra1.z, s0);
      s0 = fmaf(q1.w * k0b.w, ra1.w, s0);
      float s1 = q0.x * k1a.x * rb0v.x;
      s1 = fmaf(q0.y * k1a.y, rb0v.y, s1);
      s1 = fmaf(q0.z * k1a.z, rb0v.z, s1);
      s1 = fmaf(q0.w * k1a.w, rb0v.w, s1);
      s1 = fmaf(q1.x * k1b.x, rb1v.x, s1);
      s1 = fmaf(q1.y * k1b.y, rb1v.y, s1);
      s1 = fmaf(q1.z * k1b.z, rb1v.z, s1);
      s1 = fmaf(q1.w * k1b.w, rb1v.w, s1);
      s0 = red4(s0);
      s1 = red4(s1);
      if (dq == 0 && j < station) { ph0[j] = s0; ph1[j] = s1; }
    }
  }
  // diagonal cells j == i0+ii when beyond station (lanes 0..3 of each wave;
  // rpe/q from global -- once per block per (head, ii))
  if (j4 == 0) {
    if (dx0) {
      const int i = i0;
      const float4 r0 = *reinterpret_cast<const float4*>(rb0 + i * D_ + dq * 8);
      const float4 r1 = *reinterpret_cast<const float4*>(rb0 + i * D_ + dq * 8 + 4);
      const float4 q0 = *reinterpret_cast<const float4*>(qh + i * D_ + dq * 8);
      const float4 q1 = *reinterpret_cast<const float4*>(qh + i * D_ + dq * 8 + 4);
      float s = q0.x * k0a.x * r0.x;
      s = fmaf(q0.y * k0a.y, r0.y, s);
      s = fmaf(q0.z * k0a.z, r0.z, s);
      s = fmaf(q0.w * k0a.w, r0.w, s);
      s = fmaf(q1.x * k0b.x, r1.x, s);
      s = fmaf(q1.y * k0b.y, r1.y, s);
      s = fmaf(q1.z * k0b.z, r1.z, s);
      s = fmaf(q1.w * k0b.w, r1.w, s);
      s = red4(s);
      if (dq == 0) ph0[i] = s;
    }
    if (dx1) {
      const int i = i0 + 1;
      const float4 r0 = *reinterpret_cast<const float4*>(rb1 + i * D_ + dq * 8);
      const float4 r1 = *reinterpret_cast<const float4*>(rb1 + i * D_ + dq * 8 + 4);
      const float4 q0 = *reinterpret_cast<const float4*>(qh + i * D_ + dq * 8);
      const float4 q1 = *reinterpret_cast<const float4*>(qh + i * D_ + dq * 8 + 4);
      float s = q0.x * k1a.x * r0.x;
      s = fmaf(q0.y * k1a.y, r0.y, s);
      s = fmaf(q0.z * k1a.z, r0.z, s);
      s = fmaf(q0.w * k1a.w, r0.w, s);
      s = fmaf(q1.x * k1b.x, r1.x, s);
      s = fmaf(q1.y * k1b.y, r1.y, s);
      s = fmaf(q1.z * k1b.z, r1.z, s);
      s = fmaf(q1.w * k1b.w, r1.w, s);
      s = red4(s);
      if (dq == 0) ph1[i] = s;
    }
  }
  __syncthreads();

  // ---- softmax: wave w handles rows (ii=0,h=w) and (ii=1,h=w) ----
  #pragma unroll
  for (int ii = 0; ii < TI; ++ii) {
    float* pr = &p_smem[ii][w][0];
    const int ig = i0 + ii;
    const bool dxi = (ig >= station);
    float m = -1e30f;
    for (int jj = lane; jj < station; jj += 64) m = fmaxf(m, pr[jj]);
    const float dv = dxi ? pr[ig] : -1e30f;
    m = fmaxf(m, dv);
    #pragma unroll
    for (int o = 32; o; o >>= 1) m = fmaxf(m, __shfl_xor(m, o, 64));
    float sum = 0.f;
    for (int jj = lane; jj < station; jj += 64) {
      const float e = __expf(pr[jj] - m);
      pr[jj] = e;
      sum += e;
    }
    #pragma unroll
    for (int o = 32; o; o >>= 1) sum += __shfl_xor(sum, o, 64);
    if (dxi) {
      const float e = __expf(dv - m);
      sum += e;
      if (lane == 0) pr[ig] = e;
    }
    if (lane == 0) sums[ii][w] = sum;
  }
  __syncthreads();

  // ---- attn @ V: wave w owns head w; each V load feeds both i-rows ----
  float4 a0 = make_float4(0.f, 0.f, 0.f, 0.f);
  float4 a1 = make_float4(0.f, 0.f, 0.f, 0.f);
  {
    const float* vh = vb + w * HS;
    #pragma unroll 4
    for (int jb = 0; jb < station; jb += 8) {
      const int j  = jb + j8;
      const int jc = j < S_ ? j : S_ - 1;
      const float4 v4 = *reinterpret_cast<const float4*>(vh + jc * D_ + dc * 4);
      float pv0 = 0.f, pv1 = 0.f;
      if (j < station) { pv0 = ph0[j]; pv1 = ph1[j]; }
      a0.x = fmaf(pv0, v4.x, a0.x);
      a0.y = fmaf(pv0, v4.y, a0.y);
      a0.z = fmaf(pv0, v4.z, a0.z);
      a0.w = fmaf(pv0, v4.w, a0.w);
      a1.x = fmaf(pv1, v4.x, a1.x);
      a1.y = fmaf(pv1, v4.y, a1.y);
      a1.z = fmaf(pv1, v4.z, a1.z);
      a1.w = fmaf(pv1, v4.w, a1.w);
    }
  }
  // reduce over j8 groups (lane bits 3..5)
  #pragma unroll
  for (int o = 8; o <= 32; o <<= 1) {
    a0.x += __shfl_xor(a0.x, o, 64);
    a0.y += __shfl_xor(a0.y, o, 64);
    a0.z += __shfl_xor(a0.z, o, 64);
    a0.w += __shfl_xor(a0.w, o, 64);
    a1.x += __shfl_xor(a1.x, o, 64);
    a1.y += __shfl_xor(a1.y, o, 64);
    a1.z += __shfl_xor(a1.z, o, 64);
    a1.w += __shfl_xor(a1.w, o, 64);
  }
  if (j8 == 0) {
    // diagonal contributions (exactly once, post-reduction)
    if (dx0) {
      const float pv = ph0[i0];
      const float4 v4 = *reinterpret_cast<const float4*>(vb + w * HS + i0 * D_ + dc * 4);
      a0.x = fmaf(pv, v4.x, a0.x);
      a0.y = fmaf(pv, v4.y, a0.y);
      a0.z = fmaf(pv, v4.z, a0.z);
      a0.w = fmaf(pv, v4.w, a0.w);
    }
    if (dx1) {
      const float pv = ph1[i0 + 1];
      const float4 v4 = *reinterpret_cast<const float4*>(vb + w * HS + (i0 + 1) * D_ + dc * 4);
      a1.x = fmaf(pv, v4.x, a1.x);
      a1.y = fmaf(pv, v4.y, a1.y);
      a1.z = fmaf(pv, v4.z, a1.z);
      a1.w = fmaf(pv, v4.w, a1.w);
    }
    const float inv0 = 1.f / sums[0][w];
    const float inv1 = 1.f / sums[1][w];
    a0.x *= inv0; a0.y *= inv0; a0.z *= inv0; a0.w *= inv0;
    a1.x *= inv1; a1.y *= inv1; a1.z *= inv1; a1.w *= inv1;
    reinterpret_cast<float4*>(&orow[0][w * D_])[dc] = a0;
    reinterpret_cast<float4*>(&orow[1][w * D_])[dc] = a1;
  }
  __syncthreads();

  // ---- fc (thread per output column m=tid, first 4 waves) + residual + LN --
  float f0 = 0.f, f1 = 0.f;
  if (tid < DM_) {
    const float* wp = fc_w + tid;
    #pragma unroll 8
    for (int n4 = 0; n4 < HD_ / 4; ++n4) {
      const float4 o0 = reinterpret_cast<const float4*>(&orow[0][0])[n4];
      const float4 o1 = reinterpret_cast<const float4*>(&orow[1][0])[n4];
      const float w0 = wp[(4 * n4 + 0) * DM_];
      const float w1 = wp[(4 * n4 + 1) * DM_];
      const float w2 = wp[(4 * n4 + 2) * DM_];
      const float w3 = wp[(4 * n4 + 3) * DM_];
      f0 = fmaf(o0.x, w0, f0); f1 = fmaf(o1.x, w0, f1);
      f0 = fmaf(o0.y, w1, f0); f1 = fmaf(o1.y, w1, f1);
      f0 = fmaf(o0.z, w2, f0); f1 = fmaf(o1.z, w2, f1);
      f0 = fmaf(o0.w, w3, f0); f1 = fmaf(o1.w, w3, f1);
    }
    const float bias = fc_b[tid];
    f0 += bias + hid[(size_t)(b * S_ + i0) * DM_ + tid];
    f1 += bias + hid[(size_t)(b * S_ + i0 + 1) * DM_ + tid];
    float s0 = f0, s1 = f1;
    #pragma unroll
    for (int o = 32; o; o >>= 1) {
      s0 += __shfl_xor(s0, o, 64);
      s1 += __shfl_xor(s1, o, 64);
    }
    if (lane == 0) { redm[0][w] = s0; redm[1][w] = s1; }
  }
  __syncthreads();
  const float mu0 = (redm[0][0] + redm[0][1] + redm[0][2] + redm[0][3]) * (1.f / DM_);
  const float mu1 = (redm[1][0] + redm[1][1] + redm[1][2] + redm[1][3]) * (1.f / DM_);
  const float d0 = f0 - mu0, d1 = f1 - mu1;
  if (tid < DM_) {
    float s0 = d0 * d0, s1 = d1 * d1;
    #pragma unroll
    for (int o = 32; o; o >>= 1) {
      s0 += __shfl_xor(s0, o, 64);
      s1 += __shfl_xor(s1, o, 64);
    }
    if (lane == 0) { redvr[0][w] = s0; redvr[1][w] = s1; }
  }
  __syncthreads();
  if (tid < DM_) {
    const float v0 = (redvr[0][0] + redvr[0][1] + redvr[0][2] + redvr[0][3]) * (1.f / DM_);
    const float v1 = (redvr[1][0] + redvr[1][1] + redvr[1][2] + redvr[1][3]) * (1.f / DM_);
    const float lw = ln_w[tid], lb = ln_b[tid];
    out[(size_t)(b * S_ + i0) * DM_ + tid]     = d0 * rsqrtf(v0 + 1e-6f) * lw + lb;
    out[(size_t)(b * S_ + i0 + 1) * DM_ + tid] = d1 * rsqrtf(v1 + 1e-6f) * lw + lb;
  }
}

// ---------------------------------------------------------------------------
extern "C" void kernel_launch(void* const* d_in, const int* in_sizes, int n_in,
                              void* d_out, int out_size, void* d_ws, size_t ws_size,
                              hipStream_t stream) {
  const float* hid = (const float*)d_in[0];
  const float* rpe = (const float*)d_in[1];
  const float* wq  = (const float*)d_in[2];
  const float* wk  = (const float*)d_in[3];
  const float* wv  = (const float*)d_in[4];
  const float* fcw = (const float*)d_in[5];
  const float* fcb = (const float*)d_in[6];
  const float* lnw = (const float*)d_in[7];
  const float* lnb = (const float*)d_in[8];
  const int* station = (const int*)d_in[9];
  float* out = (float*)d_out;

  const size_t per = (size_t)B_ * H_ * S_ * D_;   // 262144 floats
  float* q_ws = (float*)d_ws;
  float* k_ws = q_ws + per;
  float* v_ws = k_ws + per;

  dim3 gA(B_ * S_ / NROW, 3);
  qkv_kernel<<<gA, 256, 0, stream>>>(hid, wq, wk, wv, q_ws, k_ws, v_ws);
  attn_fused_kernel<<<B_ * S_ / TI, 512, 0, stream>>>(
      rpe, q_ws, k_ws, v_ws, station, fcw, fcb, hid, lnw, lnb, out);
}